// Round 4
// baseline (169.270 us; speedup 1.0000x reference)
//
#include <hip/hip_runtime.h>
#include <math.h>

#define DIM 64
#define SEQ 784
#define BATCH 256

// ---------- cross-lane helpers (wave64 full reduction via DPP) ----------
template <int CTRL>
__device__ __forceinline__ float dpp_add_step(float s) {
    int v = __builtin_amdgcn_update_dpp(0, __float_as_int(s), CTRL, 0xF, 0xF, false);
    return s + __int_as_float(v);
}

// Sum across all 64 lanes; result broadcast (uniform, via readlane 63).
__device__ __forceinline__ float wave_allsum(float x) {
    x = dpp_add_step<0xB1>(x);   // quad_perm [1,0,3,2]  (xor 1)
    x = dpp_add_step<0x4E>(x);   // quad_perm [2,3,0,1]  (xor 2)
    x = dpp_add_step<0x141>(x);  // row_half_mirror      (pairs across quads)
    x = dpp_add_step<0x140>(x);  // row_mirror           (pairs across 8-groups)
    x = dpp_add_step<0x142>(x);  // row_bcast15          (16 -> 32)
    x = dpp_add_step<0x143>(x);  // row_bcast31          (32 -> 64, lane63 = total)
    return __int_as_float(__builtin_amdgcn_readlane(__float_as_int(x), 63));
}

__device__ __forceinline__ float gelu_exact(float v) {
    return 0.5f * v * (1.0f + erff(v * 0.70710678118654752440f));
}

// ---------- manual VMEM: compiler emits NO waitcnt for asm loads ----------
typedef float f32x4_t __attribute__((ext_vector_type(4)));

__device__ __forceinline__ float gload_f32(const float* p) {
    float r;
    asm volatile("global_load_dword %0, %1, off" : "=v"(r) : "v"(p));
    return r;
}
__device__ __forceinline__ f32x4_t gload_f32x4(const float* p) {
    f32x4_t r;
    asm volatile("global_load_dwordx4 %0, %1, off" : "=v"(r) : "v"(p));
    return r;
}
// Counted wait + hard scheduling fence (VALU can hoist past an asm waitcnt
// despite the "memory" clobber; sched_barrier(0) right after is the fix).
#define VMWAIT(N)                                                   \
    do {                                                            \
        asm volatile("s_waitcnt vmcnt(" #N ")" ::: "memory");       \
        __builtin_amdgcn_sched_barrier(0);                          \
    } while (0)

// ---------- prepass: k[b,s,:] and alpha[b,s] for all rows ----------
// Known-good __syncthreads structure (R2, absmax 0.0), but launched as
// 4096 blocks x 64 threads: barriers in a single-wave block keep identical
// semantics while costing only wave-local waits (no cross-wave coupling,
// no full-block store drain).
__global__ __launch_bounds__(64) void prepass_kernel(
    const float* __restrict__ x, const float* __restrict__ W_in,
    const float* __restrict__ pos_emb, const float* __restrict__ Wk,
    const float* __restrict__ Wb, const float* __restrict__ bbp,
    float* __restrict__ k_ws, float* __restrict__ alpha_ws)
{
    const int lane = threadIdx.x;
    const int gw   = blockIdx.x;              // 0..4095
    const int b    = gw >> 4;                 // /16
    const int s0   = (gw & 15) * 49;

    float4 wkr[16];
    const float4* wk4 = (const float4*)(Wk + lane * 64);  // lane owns Wk row `lane`
#pragma unroll
    for (int i = 0; i < 16; ++i) wkr[i] = wk4[i];
    const float win = W_in[lane];
    const float wb  = Wb[lane];
    const float bb  = bbp[0];

    __shared__ __align__(16) float hbuf[64];

    for (int r = 0; r < 49; ++r) {
        const int s = s0 + r;
        const float xs = x[b * SEQ + s];
        const float pe = pos_emb[s * 64 + lane];
        const float h  = gelu_exact(fmaf(xs, win, pe));
        const float bdot = wave_allsum(h * wb);
        __syncthreads();               // prior iteration's reads done
        hbuf[lane] = h;
        __syncthreads();
        const float4* h4 = (const float4*)hbuf;
        float kd = 0.f;
#pragma unroll
        for (int i = 0; i < 16; ++i) {
            float4 hv = h4[i];
            kd = fmaf(hv.x, wkr[i].x, kd);
            kd = fmaf(hv.y, wkr[i].y, kd);
            kd = fmaf(hv.z, wkr[i].z, kd);
            kd = fmaf(hv.w, wkr[i].w, kd);
        }
        float lam = wave_allsum(kd * kd);
        lam = fmaxf(lam, 1e-6f);
        const float beta = 1.0f / (1.0f + expf(-(bdot + bb)));
        const float al   = -expm1f(-beta * lam) / (lam + 1e-6f);
        const int row = b * SEQ + s;
        k_ws[row * 64 + lane] = kd;
        if (lane == 0) alpha_ws[row] = al;
    }
}

// ---------- shared epilogue (fused fallback only) ----------
__device__ __forceinline__ void epilogue(
    int b, int lane, float w, float* sh,
    const float* __restrict__ Wv, const float* __restrict__ ln_g,
    const float* __restrict__ ln_b, const float* __restrict__ Wc,
    const float* __restrict__ bc, float* __restrict__ out)
{
    __syncthreads();
    sh[lane] = w;
    __syncthreads();
    float last = 0.f;
    const float4* wv4 = (const float4*)(Wv + lane * 64);
    const float4* w4  = (const float4*)sh;
#pragma unroll
    for (int i = 0; i < 16; ++i) {
        float4 hv = w4[i], vv = wv4[i];
        last = fmaf(hv.x, vv.x, last);
        last = fmaf(hv.y, vv.y, last);
        last = fmaf(hv.z, vv.z, last);
        last = fmaf(hv.w, vv.w, last);
    }
    const float mu  = wave_allsum(last) * 0.015625f;
    const float dd  = last - mu;
    const float var = wave_allsum(dd * dd) * 0.015625f;
    const float ln  = dd / sqrtf(var + 1e-5f) * ln_g[lane] + ln_b[lane];
    __syncthreads();
    sh[lane] = ln;
    __syncthreads();
    if (lane < 10) {
        float acc = bc[lane];
        const float* wc = Wc + lane * 64;
#pragma unroll
        for (int j = 0; j < 64; ++j) acc = fmaf(wc[j], sh[j], acc);
        out[b * 10 + lane] = acc;
    }
}

// ---------- backward scan, a-sequence only: one wave per batch ----------
// Pair-Gram regroup (exact; validated R1/R2). 2-deep inline-asm prefetch:
// 20 VMEM per chunk (16 k dwords + 4 uniform dwordx4 alpha); max 40
// outstanding; steady wait vmcnt(20). NO global ops inside the counted
// loop (a's park in LDS; ds ops are lgkmcnt, invisible to vmcnt). 2-deep
// keeps data regs at ~64 so no scratch spills can corrupt the counts.
__global__ __launch_bounds__(64) void scan_a_kernel(
    const float* __restrict__ x, const float* __restrict__ pos_emb,
    const float* __restrict__ W_in, const float* __restrict__ Wq,
    const float* __restrict__ k_ws, float* ab /* alpha in, a out */)
{
    const int lane = threadIdx.x;
    const int b    = blockIdx.x;
    __shared__ __align__(16) float sh[64];
    __shared__ __align__(16) float a_lds[SEQ];

    // u init: q at last position
    {
        const float h = gelu_exact(fmaf(x[b * SEQ + 783], W_in[lane], pos_emb[783 * 64 + lane]));
        sh[lane] = h;
    }
    __syncthreads();
    float u = 0.f;
    {
        const float4* wq4 = (const float4*)(Wq + lane * 64);
        const float4* h4  = (const float4*)sh;
#pragma unroll
        for (int i = 0; i < 16; ++i) {
            float4 hv = h4[i], qv = wq4[i];
            u = fmaf(hv.x, qv.x, u);
            u = fmaf(hv.y, qv.y, u);
            u = fmaf(hv.z, qv.z, u);
            u = fmaf(hv.w, qv.w, u);
        }
    }

    const float* kb  = k_ws + (size_t)b * SEQ * 64;
    float*       abp = ab + b * SEQ;

    float K0[16], A0[16], K1[16], A1[16];
    float aout[16];

#define LOADC(K, A, c)                                         \
    do {                                                       \
        const int tb_ = 783 - (c) * 16;                        \
        _Pragma("unroll")                                      \
        for (int i = 0; i < 16; ++i)                           \
            K[i] = gload_f32(&kb[(tb_ - i) * 64 + lane]);      \
        _Pragma("unroll")                                      \
        for (int q = 0; q < 4; ++q) {                          \
            const f32x4_t av = gload_f32x4(&abp[tb_ - 15 + q * 4]); \
            A[15 - (q * 4 + 0)] = av[0];                       \
            A[15 - (q * 4 + 1)] = av[1];                       \
            A[15 - (q * 4 + 2)] = av[2];                       \
            A[15 - (q * 4 + 3)] = av[3];                       \
        }                                                      \
    } while (0)

#define COMPC(K, A, c)                                         \
    do {                                                       \
        _Pragma("unroll")                                      \
        for (int g = 0; g < 8; ++g) {                          \
            const int i0 = 2 * g, i1 = 2 * g + 1;              \
            const float d0  = wave_allsum(u * K[i0]);          \
            const float e1  = wave_allsum(u * K[i1]);          \
            const float g01 = wave_allsum(K[i0] * K[i1]);      \
            const float a0  = A[i0] * d0;                      \
            const float d1  = fmaf(-a0, g01, e1);              \
            const float a1  = A[i1] * d1;                      \
            u = fmaf(-a0, K[i0], u);                           \
            u = fmaf(-a1, K[i1], u);                           \
            aout[i0] = a0; aout[i1] = a1;                      \
        }                                                      \
        if (lane == 0) {                                       \
            const int tb_ = 783 - (c) * 16;                    \
            _Pragma("unroll")                                  \
            for (int i = 0; i < 16; ++i)                       \
                a_lds[tb_ - i] = aout[i];                      \
        }                                                      \
    } while (0)

    // Drain prologue's compiler-generated VMEM so our counts start at 0.
    VMWAIT(0);
    // 2-deep pipeline: issue chunk c+1, wait chunk c, compute chunk c.
    LOADC(K0, A0, 0);                       // 20 outstanding
    for (int c = 0; c < 48; c += 2) {
        LOADC(K1, A1, c + 1);               // <=40 outstanding
        VMWAIT(20);                         // chunk c complete
        COMPC(K0, A0, c);
        LOADC(K0, A0, c + 2);               // c+2 <= 48, always valid
        VMWAIT(20);                         // chunk c+1 complete
        COMPC(K1, A1, c + 1);
    }
    VMWAIT(0);                              // chunk 48 complete
    COMPC(K0, A0, 48);
#undef LOADC
#undef COMPC

    // flush a-sequence to global (overwrites alpha_ws in place)
    asm volatile("s_waitcnt lgkmcnt(0)" ::: "memory");
#pragma unroll
    for (int j = 0; j < 13; ++j) {
        const int idx = j * 64 + lane;
        if (idx < SEQ) abp[idx] = a_lds[idx];
    }
}

// ---------- w accumulation + epilogue at higher occupancy ----------
// grid: 256 blocks x 512 thr (8 waves). Block b: w = sum_t a_t * h_t,
// 98 steps per wave, block-reduced; wave 0 runs the epilogue.
__global__ __launch_bounds__(512) void wsum_kernel(
    const float* __restrict__ x, const float* __restrict__ W_in,
    const float* __restrict__ pos_emb, const float* __restrict__ a_ws,
    const float* __restrict__ Wv, const float* __restrict__ ln_g,
    const float* __restrict__ ln_b, const float* __restrict__ Wc,
    const float* __restrict__ bc, float* __restrict__ out)
{
    const int lane = threadIdx.x & 63;
    const int wv   = threadIdx.x >> 6;        // 0..7
    const int b    = blockIdx.x;
    const float win = W_in[lane];
    const float* ap = a_ws + b * SEQ;
    const float* xp = x + b * SEQ;

    float w = 0.f;
    const int t0 = wv * 98;
#pragma unroll 2
    for (int i = 0; i < 98; ++i) {
        const int t = t0 + i;
        const float h = gelu_exact(fmaf(xp[t], win, pos_emb[t * 64 + lane]));
        w = fmaf(ap[t], h, w);
    }

    __shared__ __align__(16) float swr[8][64];
    __shared__ __align__(16) float sh[64];
    swr[wv][lane] = w;
    __syncthreads();
    if (wv != 0) return;

    w = swr[0][lane] + swr[1][lane] + swr[2][lane] + swr[3][lane]
      + swr[4][lane] + swr[5][lane] + swr[6][lane] + swr[7][lane];
    sh[lane] = w;
    asm volatile("s_waitcnt lgkmcnt(0)" ::: "memory");
    float last = 0.f;
    const float4* wv4 = (const float4*)(Wv + lane * 64);
    const float4* w4  = (const float4*)sh;
#pragma unroll
    for (int i = 0; i < 16; ++i) {
        float4 hv = w4[i], vv = wv4[i];
        last = fmaf(hv.x, vv.x, last);
        last = fmaf(hv.y, vv.y, last);
        last = fmaf(hv.z, vv.z, last);
        last = fmaf(hv.w, vv.w, last);
    }
    const float mu  = wave_allsum(last) * 0.015625f;
    const float dd  = last - mu;
    const float var = wave_allsum(dd * dd) * 0.015625f;
    const float ln  = dd / sqrtf(var + 1e-5f) * ln_g[lane] + ln_b[lane];
    asm volatile("s_waitcnt lgkmcnt(0)" ::: "memory");
    sh[lane] = ln;
    asm volatile("s_waitcnt lgkmcnt(0)" ::: "memory");
    if (lane < 10) {
        float acc = bc[lane];
        const float* wc = Wc + lane * 64;
#pragma unroll
        for (int j = 0; j < 64; ++j) acc = fmaf(wc[j], sh[j], acc);
        out[b * 10 + lane] = acc;
    }
}

// ---------- fused fallback (no workspace needed) ----------
__global__ __launch_bounds__(64) void fused_kernel(
    const float* __restrict__ x, const float* __restrict__ W_in,
    const float* __restrict__ pos_emb, const float* __restrict__ Wq,
    const float* __restrict__ Wk, const float* __restrict__ Wv,
    const float* __restrict__ Wb, const float* __restrict__ bbp,
    const float* __restrict__ ln_g, const float* __restrict__ ln_b,
    const float* __restrict__ Wc, const float* __restrict__ bc,
    float* __restrict__ out)
{
    const int lane = threadIdx.x;
    const int b    = blockIdx.x;
    __shared__ __align__(16) float sh[64];
    const float win = W_in[lane];
    const float wb  = Wb[lane];
    const float bb  = bbp[0];

    float4 wkr[16];
    const float4* wk4 = (const float4*)(Wk + lane * 64);
#pragma unroll
    for (int i = 0; i < 16; ++i) wkr[i] = wk4[i];

    float u;
    {
        const float h = gelu_exact(fmaf(x[b * SEQ + 783], win, pos_emb[783 * 64 + lane]));
        sh[lane] = h;
        __syncthreads();
        u = 0.f;
        const float4* wq4 = (const float4*)(Wq + lane * 64);
        const float4* h4  = (const float4*)sh;
#pragma unroll
        for (int i = 0; i < 16; ++i) {
            float4 hv = h4[i], qv = wq4[i];
            u = fmaf(hv.x, qv.x, u);
            u = fmaf(hv.y, qv.y, u);
            u = fmaf(hv.z, qv.z, u);
            u = fmaf(hv.w, qv.w, u);
        }
    }
    float w = 0.f;
    for (int t = 783; t >= 0; --t) {
        const float h = gelu_exact(fmaf(x[b * SEQ + t], win, pos_emb[t * 64 + lane]));
        const float bdot = wave_allsum(h * wb);
        __syncthreads();
        sh[lane] = h;
        __syncthreads();
        float kd = 0.f;
        const float4* h4 = (const float4*)sh;
#pragma unroll
        for (int i = 0; i < 16; ++i) {
            float4 hv = h4[i];
            kd = fmaf(hv.x, wkr[i].x, kd);
            kd = fmaf(hv.y, wkr[i].y, kd);
            kd = fmaf(hv.z, wkr[i].z, kd);
            kd = fmaf(hv.w, wkr[i].w, kd);
        }
        float lam = wave_allsum(kd * kd);
        lam = fmaxf(lam, 1e-6f);
        const float beta = 1.0f / (1.0f + expf(-(bdot + bb)));
        const float al   = -expm1f(-beta * lam) / (lam + 1e-6f);
        const float dot  = wave_allsum(u * kd);
        const float a    = al * dot;
        u = fmaf(-a, kd, u);
        w = fmaf(a, h, w);
    }
    epilogue(b, lane, w, sh, Wv, ln_g, ln_b, Wc, bc, out);
}

extern "C" void kernel_launch(void* const* d_in, const int* in_sizes, int n_in,
                              void* d_out, int out_size, void* d_ws, size_t ws_size,
                              hipStream_t stream)
{
    const float* x       = (const float*)d_in[0];
    const float* W_in    = (const float*)d_in[1];
    const float* pos_emb = (const float*)d_in[2];
    const float* Wq      = (const float*)d_in[3];
    const float* Wk      = (const float*)d_in[4];
    const float* Wv      = (const float*)d_in[5];
    const float* Wb      = (const float*)d_in[6];
    const float* bb      = (const float*)d_in[7];
    const float* ln_g    = (const float*)d_in[8];
    const float* ln_b    = (const float*)d_in[9];
    const float* Wc      = (const float*)d_in[10];
    const float* bc      = (const float*)d_in[11];
    float* out = (float*)d_out;

    const size_t k_elems = (size_t)BATCH * SEQ * 64;
    const size_t need = k_elems * sizeof(float) + (size_t)BATCH * SEQ * sizeof(float);

    if (ws_size >= need) {
        float* k_ws     = (float*)d_ws;
        float* alpha_ws = k_ws + k_elems;
        prepass_kernel<<<4096, 64, 0, stream>>>(x, W_in, pos_emb, Wk, Wb, bb, k_ws, alpha_ws);
        scan_a_kernel<<<BATCH, 64, 0, stream>>>(x, pos_emb, W_in, Wq, k_ws, alpha_ws);
        wsum_kernel<<<BATCH, 512, 0, stream>>>(x, W_in, pos_emb, alpha_ws, Wv, ln_g, ln_b,
                                               Wc, bc, out);
    } else {
        fused_kernel<<<BATCH, 64, 0, stream>>>(x, W_in, pos_emb, Wq, Wk, Wv, Wb, bb,
                                               ln_g, ln_b, Wc, bc, out);
    }
}